// Round 7
// baseline (146.071 us; speedup 1.0000x reference)
//
#include <hip/hip_runtime.h>

#define PRIME1 2654435761u
#define PRIME2 805459861u
#define PRIME3 3674653429u

typedef float f2v __attribute__((ext_vector_type(2)));
typedef float f4v __attribute__((ext_vector_type(4)));

// Level-major mapping: each block = 256 points x ONE level; (blockIdx % 8)
// == (level % 8) so each XCD's L2 holds a single ~4MB level table.
// Main loop is at the per-CU miss-queue*latency ceiling (~107us model);
// this round attacks XCD load imbalance: dense levels 0-2 are ~0.65x cost,
// so XCDs 0-2 idle at the tail. Donate the last 64 chunks of levels 11-15
// to tail blocks with b%8 in {0,1,2} (runs on XCDs 0-2 after their own work).
template <bool DIRECT>
__global__ __launch_bounds__(256) void hash_enc_kernel(
    const float* __restrict__ xyzts,        // [npts,4]
    const float* __restrict__ table,        // [total]
    const int* __restrict__ shapes,         // [16,4]
    const unsigned int* __restrict__ sizes, // [16]
    const int* __restrict__ indicator,      // [16]
    const int* __restrict__ offsets,        // [16]
    float* __restrict__ dst,                // ws [16,npts,2] or out [npts,32]
    int npts, int nchunks, int rebalance)
{
    int b = blockIdx.x;
    int main_blocks = nchunks * 16;
    int level, chunk;
    if (b >= main_blocks) {
        // donated tail region: only XCD residues 0..2 do work,
        // level-clustered (w>>6) so each donor XCD swaps tables rarely
        int i = b - main_blocks;
        int r = i & 7;
        if (r >= 3) return;
        int w = (i >> 3) * 3 + r;
        if (w >= 320) return;
        level = 11 + (w >> 6);          // 5 levels x 64 chunks
        chunk = 448 + (w & 63);
    } else {
        int half = b / (nchunks * 8);             // 0 -> levels 0..7, 1 -> 8..15
        int within = b % (nchunks * 8);
        level = (within & 7) + (half << 3);       // uniform in the block
        chunk = within >> 3;
        if (rebalance && level >= 11 && chunk >= 448) return;  // donated away
    }
    int n = chunk * 256 + (int)threadIdx.x;
    if (n >= npts) return;

    // level is wave-uniform -> scalar loads
    int4 rs = reinterpret_cast<const int4*>(shapes)[level];
    unsigned int size = sizes[level];
    unsigned int msk = size - 1u;       // indicator==0 => size == 2^19 (pow2)
    bool ind = (indicator[level] != 0);
    int off = offsets[level];

    // NT point load: don't let the xyzts stream evict table lines
    f4v x = __builtin_nontemporal_load(
        reinterpret_cast<const f4v*>(xyzts) + n);

    float r0 = (float)rs.x, r1 = (float)rs.y, r2 = (float)rs.z, r3 = (float)rs.w;
    float p0 = x.x * r0, p1 = x.y * r1, p2 = x.z * r2, p3 = x.w * r3;
    float g0 = fminf(fmaxf(floorf(p0), 0.f), r0 - 1.f);
    float g1 = fminf(fmaxf(floorf(p1), 0.f), r1 - 1.f);
    float g2 = fminf(fmaxf(floorf(p2), 0.f), r2 - 1.f);
    float g3 = fminf(fmaxf(floorf(p3), 0.f), r3 - 1.f);
    float f0 = fminf(fmaxf(p0 - g0, 0.f), 1.f);
    float f1 = fminf(fmaxf(p1 - g1, 0.f), 1.f);
    float f2 = fminf(fmaxf(p2 - g2, 0.f), 1.f);
    float f3 = fminf(fmaxf(p3 - g3, 0.f), 1.f);
    unsigned int u0 = (unsigned int)g0, u1 = (unsigned int)g1;
    unsigned int u2 = (unsigned int)g2, u3 = (unsigned int)g3;

    unsigned int s1 = (unsigned int)(rs.x + 1);
    unsigned int s2 = s1 * (unsigned int)(rs.y + 1);
    unsigned int s3 = s2 * (unsigned int)(rs.z + 1);

    unsigned int a1 = u1 * PRIME1, a2 = u2 * PRIME2, a3 = u3 * PRIME3;
    unsigned int xb = u0 ^ a1 ^ a2 ^ a3;
    unsigned int e0 = u0 ^ (u0 + 1u);
    unsigned int e1 = a1 ^ ((u1 + 1u) * PRIME1);
    unsigned int e2 = a2 ^ ((u2 + 1u) * PRIME2);
    unsigned int e3 = a3 ^ ((u3 + 1u) * PRIME3);

    unsigned int ab = u0 + u1 * s1 + u2 * s2 + u3 * s3;

    float om0 = 1.f - f0, om1 = 1.f - f1, om2 = 1.f - f2, om3 = 1.f - f3;

    const float* tb = table + off;

    // Phase 1: all 16 corner indices
    unsigned int idx[16];
#pragma unroll
    for (int c = 0; c < 16; ++c) {
        unsigned int hf = xb, hu = ab;
        if (c & 1) { hf ^= e0; hu += 1u; }
        if (c & 2) { hf ^= e1; hu += s1; }
        if (c & 4) { hf ^= e2; hu += s2; }
        if (c & 8) { hf ^= e3; hu += s3; }
        idx[c] = ind ? hu : (hf & msk);
    }

    // Phase 2: issue all 16 independent gathers
    f2v v[16];
#pragma unroll
    for (int c = 0; c < 16; ++c)
        v[c] = *reinterpret_cast<const f2v*>(tb + 2u * idx[c]);

    // Phase 3: weighted accumulate
    float acc0 = 0.f, acc1 = 0.f;
#pragma unroll
    for (int c = 0; c < 16; ++c) {
        float w = (c & 1) ? f0 : om0;
        w *= (c & 2) ? f1 : om1;
        w *= (c & 4) ? f2 : om2;
        w *= (c & 8) ? f3 : om3;
        acc0 += w * v[c].x;
        acc1 += w * v[c].y;
    }

    f2v res;
    res.x = acc0; res.y = acc1;
    if (DIRECT) {
        reinterpret_cast<f2v*>(dst)[(size_t)n * 16 + level] = res;
    } else {
        // coalesced full-line streaming store; keep it out of L2 (table owns L2)
        __builtin_nontemporal_store(
            res, reinterpret_cast<f2v*>(dst) + (size_t)level * npts + n);
    }
}

// ws [16][npts] float2 -> out [npts][32] float. 2 points per thread, all-f4v.
__global__ __launch_bounds__(256) void transpose2_kernel(
    const float* __restrict__ ws, float* __restrict__ out, int npts)
{
    int t = blockIdx.x * 256 + (int)threadIdx.x;
    int n0 = t * 2;
    if (n0 >= npts) return;
    int hp = npts >> 1;
    const f4v* w = reinterpret_cast<const f4v*>(ws);
    f4v v[16];   // v[l] = {ws[l][n0].x, .y, ws[l][n0+1].x, .y}
#pragma unroll
    for (int l = 0; l < 16; ++l)
        v[l] = __builtin_nontemporal_load(w + (size_t)l * hp + t);
    f4v* o = reinterpret_cast<f4v*>(out + (size_t)n0 * 32);
#pragma unroll
    for (int j = 0; j < 8; ++j) {
        f4v q0, q1;
        q0.x = v[2 * j].x; q0.y = v[2 * j].y;
        q0.z = v[2 * j + 1].x; q0.w = v[2 * j + 1].y;
        q1.x = v[2 * j].z; q1.y = v[2 * j].w;
        q1.z = v[2 * j + 1].z; q1.w = v[2 * j + 1].w;
        __builtin_nontemporal_store(q0, o + j);
        __builtin_nontemporal_store(q1, o + 8 + j);
    }
}

// fallback scalar transpose (odd npts)
__global__ __launch_bounds__(256) void transpose_kernel(
    const float* __restrict__ ws, float* __restrict__ out, int npts)
{
    int n = blockIdx.x * 256 + (int)threadIdx.x;
    if (n >= npts) return;
    const f2v* w = reinterpret_cast<const f2v*>(ws);
    f2v v[16];
#pragma unroll
    for (int l = 0; l < 16; ++l)
        v[l] = w[(size_t)l * npts + n];
    f4v* o = reinterpret_cast<f4v*>(out + (size_t)n * 32);
#pragma unroll
    for (int j = 0; j < 8; ++j) {
        f4v q;
        q.x = v[2 * j].x; q.y = v[2 * j].y;
        q.z = v[2 * j + 1].x; q.w = v[2 * j + 1].y;
        __builtin_nontemporal_store(q, o + j);
    }
}

extern "C" void kernel_launch(void* const* d_in, const int* in_sizes, int n_in,
                              void* d_out, int out_size, void* d_ws, size_t ws_size,
                              hipStream_t stream) {
    const float* xyzts = (const float*)d_in[0];
    const float* table = (const float*)d_in[1];
    const int* shapes = (const int*)d_in[2];
    const unsigned int* sizes = (const unsigned int*)d_in[3];
    const int* indicator = (const int*)d_in[4];
    const int* offsets = (const int*)d_in[5];
    float* out = (float*)d_out;

    int npts = in_sizes[0] / 4;
    int nchunks = (npts + 255) / 256;
    // donation scheme assumes exactly 512 full chunks (npts == 131072)
    int rebalance = (nchunks == 512 && npts == nchunks * 256) ? 1 : 0;
    int blocks = nchunks * 16 + (rebalance ? 107 * 8 : 0);  // 107*3=321>=320 workers

    size_t ws_needed = (size_t)npts * 16 * 2 * sizeof(float);
    if (ws_size >= ws_needed) {
        float* ws = (float*)d_ws;
        hash_enc_kernel<false><<<blocks, 256, 0, stream>>>(
            xyzts, table, shapes, sizes, indicator, offsets, ws, npts, nchunks,
            rebalance);
        if ((npts & 1) == 0) {
            int t = npts >> 1;
            transpose2_kernel<<<(t + 255) / 256, 256, 0, stream>>>(ws, out, npts);
        } else {
            transpose_kernel<<<nchunks, 256, 0, stream>>>(ws, out, npts);
        }
    } else {
        hash_enc_kernel<true><<<blocks, 256, 0, stream>>>(
            xyzts, table, shapes, sizes, indicator, offsets, out, npts, nchunks,
            rebalance);
    }
}

// Round 8
// 108.690 us; speedup vs baseline: 1.3439x; 1.3439x over previous
//
#include <hip/hip_runtime.h>

#define PRIME1 2654435761u
#define PRIME2 805459861u
#define PRIME3 3674653429u

typedef float f2v __attribute__((ext_vector_type(2)));
typedef float f4v __attribute__((ext_vector_type(4)));

// Level-major mapping: each block = 256 points x ONE level; (blockIdx % 8)
// == (level % 8) so each XCD's L2 holds a single ~4MB level table.
// Main loop is at the per-CU MSHR*latency ceiling (~108us model floor):
// ~12 distinct 64B lines per wave-gather, ~64 outstanding misses/CU,
// ~200cy L2-hit latency. Rebalancing across XCDs was tried (R7) and
// regressed: donated levels double-fetch tables at L3 latency.
template <bool DIRECT>
__global__ __launch_bounds__(256) void hash_enc_kernel(
    const float* __restrict__ xyzts,        // [npts,4]
    const float* __restrict__ table,        // [total]
    const int* __restrict__ shapes,         // [16,4]
    const unsigned int* __restrict__ sizes, // [16]
    const int* __restrict__ indicator,      // [16]
    const int* __restrict__ offsets,        // [16]
    float* __restrict__ dst,                // ws [16,npts,2] or out [npts,32]
    int npts, int nchunks)
{
    int b = blockIdx.x;
    int half = b / (nchunks * 8);             // 0 -> levels 0..7, 1 -> 8..15
    int within = b % (nchunks * 8);
    int level = (within & 7) + (half << 3);   // uniform in the block
    int chunk = within >> 3;
    int n = chunk * 256 + (int)threadIdx.x;
    if (n >= npts) return;

    // level is wave-uniform -> scalar loads
    int4 rs = reinterpret_cast<const int4*>(shapes)[level];
    unsigned int size = sizes[level];
    unsigned int msk = size - 1u;       // indicator==0 => size == 2^19 (pow2)
    bool ind = (indicator[level] != 0);
    int off = offsets[level];

    // NT point load: don't let the xyzts stream evict table lines
    f4v x = __builtin_nontemporal_load(
        reinterpret_cast<const f4v*>(xyzts) + n);

    float r0 = (float)rs.x, r1 = (float)rs.y, r2 = (float)rs.z, r3 = (float)rs.w;
    float p0 = x.x * r0, p1 = x.y * r1, p2 = x.z * r2, p3 = x.w * r3;
    float g0 = fminf(fmaxf(floorf(p0), 0.f), r0 - 1.f);
    float g1 = fminf(fmaxf(floorf(p1), 0.f), r1 - 1.f);
    float g2 = fminf(fmaxf(floorf(p2), 0.f), r2 - 1.f);
    float g3 = fminf(fmaxf(floorf(p3), 0.f), r3 - 1.f);
    float f0 = fminf(fmaxf(p0 - g0, 0.f), 1.f);
    float f1 = fminf(fmaxf(p1 - g1, 0.f), 1.f);
    float f2 = fminf(fmaxf(p2 - g2, 0.f), 1.f);
    float f3 = fminf(fmaxf(p3 - g3, 0.f), 1.f);
    unsigned int u0 = (unsigned int)g0, u1 = (unsigned int)g1;
    unsigned int u2 = (unsigned int)g2, u3 = (unsigned int)g3;

    unsigned int s1 = (unsigned int)(rs.x + 1);
    unsigned int s2 = s1 * (unsigned int)(rs.y + 1);
    unsigned int s3 = s2 * (unsigned int)(rs.z + 1);

    unsigned int a1 = u1 * PRIME1, a2 = u2 * PRIME2, a3 = u3 * PRIME3;
    unsigned int xb = u0 ^ a1 ^ a2 ^ a3;
    unsigned int e0 = u0 ^ (u0 + 1u);
    unsigned int e1 = a1 ^ ((u1 + 1u) * PRIME1);
    unsigned int e2 = a2 ^ ((u2 + 1u) * PRIME2);
    unsigned int e3 = a3 ^ ((u3 + 1u) * PRIME3);

    unsigned int ab = u0 + u1 * s1 + u2 * s2 + u3 * s3;

    float om0 = 1.f - f0, om1 = 1.f - f1, om2 = 1.f - f2, om3 = 1.f - f3;

    const float* tb = table + off;

    // Phase 1: all 16 corner indices
    unsigned int idx[16];
#pragma unroll
    for (int c = 0; c < 16; ++c) {
        unsigned int hf = xb, hu = ab;
        if (c & 1) { hf ^= e0; hu += 1u; }
        if (c & 2) { hf ^= e1; hu += s1; }
        if (c & 4) { hf ^= e2; hu += s2; }
        if (c & 8) { hf ^= e3; hu += s3; }
        idx[c] = ind ? hu : (hf & msk);
    }

    // Phase 2: issue all 16 independent gathers (max MLP)
    f2v v[16];
#pragma unroll
    for (int c = 0; c < 16; ++c)
        v[c] = *reinterpret_cast<const f2v*>(tb + 2u * idx[c]);

    // Phase 3: weighted accumulate
    float acc0 = 0.f, acc1 = 0.f;
#pragma unroll
    for (int c = 0; c < 16; ++c) {
        float w = (c & 1) ? f0 : om0;
        w *= (c & 2) ? f1 : om1;
        w *= (c & 4) ? f2 : om2;
        w *= (c & 8) ? f3 : om3;
        acc0 += w * v[c].x;
        acc1 += w * v[c].y;
    }

    f2v res;
    res.x = acc0; res.y = acc1;
    if (DIRECT) {
        reinterpret_cast<f2v*>(dst)[(size_t)n * 16 + level] = res;
    } else {
        // coalesced full-line streaming store; keep it out of L2 (table owns L2)
        __builtin_nontemporal_store(
            res, reinterpret_cast<f2v*>(dst) + (size_t)level * npts + n);
    }
}

// ws [16][npts] float2 -> out [npts][32] float.
// 8 threads per point: tid = n*8 + c; thread writes out[n][4c..4c+3] as one
// f4v. Consecutive lanes -> consecutive 16B chunks -> each wave-store is 1KB
// fully contiguous (full-line NT stores; no 128B-stride partial lines).
// Reads: lanes sharing c read 8 consecutive n -> 64B segments, 16 lines/instr.
__global__ __launch_bounds__(256) void untranspose_kernel(
    const float* __restrict__ ws, float* __restrict__ out, int npts)
{
    int tid = blockIdx.x * 256 + (int)threadIdx.x;
    if (tid >= npts * 8) return;
    int n = tid >> 3;
    int c = tid & 7;
    const f2v* w = reinterpret_cast<const f2v*>(ws);
    f2v a = __builtin_nontemporal_load(w + (size_t)(2 * c) * npts + n);
    f2v b = __builtin_nontemporal_load(w + (size_t)(2 * c + 1) * npts + n);
    f4v q;
    q.x = a.x; q.y = a.y; q.z = b.x; q.w = b.y;
    __builtin_nontemporal_store(
        q, reinterpret_cast<f4v*>(out) + (size_t)n * 8 + c);
}

extern "C" void kernel_launch(void* const* d_in, const int* in_sizes, int n_in,
                              void* d_out, int out_size, void* d_ws, size_t ws_size,
                              hipStream_t stream) {
    const float* xyzts = (const float*)d_in[0];
    const float* table = (const float*)d_in[1];
    const int* shapes = (const int*)d_in[2];
    const unsigned int* sizes = (const unsigned int*)d_in[3];
    const int* indicator = (const int*)d_in[4];
    const int* offsets = (const int*)d_in[5];
    float* out = (float*)d_out;

    int npts = in_sizes[0] / 4;
    int nchunks = (npts + 255) / 256;
    int blocks = nchunks * 16;

    size_t ws_needed = (size_t)npts * 16 * 2 * sizeof(float);
    if (ws_size >= ws_needed) {
        float* ws = (float*)d_ws;
        hash_enc_kernel<false><<<blocks, 256, 0, stream>>>(
            xyzts, table, shapes, sizes, indicator, offsets, ws, npts, nchunks);
        int t = npts * 8;
        untranspose_kernel<<<(t + 255) / 256, 256, 0, stream>>>(ws, out, npts);
    } else {
        hash_enc_kernel<true><<<blocks, 256, 0, stream>>>(
            xyzts, table, shapes, sizes, indicator, offsets, out, npts, nchunks);
    }
}